// Round 5
// baseline (271.559 us; speedup 1.0000x reference)
//
#include <hip/hip_runtime.h>
#include <hip/hip_bf16.h>
#include <math.h>

#define H 192
#define W 192
#define CIN 32
#define COUT 64
#define BATCH 16

#define WSEG 64                     // conv cols per block
#define WI_N 66                     // staged cols (WSEG + 2 halo)
#define NSLOT 6                     // LDS row ring
#define SLOT_BYTES (WI_N * 64)      // 66 wi * 32 ci * 2B = 4224
#define GRAN 264                    // granules per row = WI_N * 4

#define WP_BYTES ((size_t)9 * COUT * CIN * 2)
#define ACC_OFF  WP_BYTES
#define ACC_BYTES ((size_t)BATCH * COUT * 4)

typedef __attribute__((ext_vector_type(8)))  short bf16x8;
typedef __attribute__((ext_vector_type(16))) float f32x16;

static __device__ __forceinline__ short f2bf(float f) {
  __hip_bfloat16 h = __float2bfloat16(f);
  return __builtin_bit_cast(short, h);
}

// slot byte addr + XOR swizzle (both write & read sides, bijective)
static __device__ __forceinline__ int lds_addr(int s, int wi, int g) {
  int a = s * SLOT_BYTES + wi * 64 + g * 16;
  return a ^ ((wi & 7) << 4);
}

// weight [ci][co][kh][kw] f32 -> Wp[tap][co][ci] bf16 (flipped); also zeroes accum
__global__ void pack_weights(const float* __restrict__ wsrc, short* __restrict__ wp,
                             float* __restrict__ accum) {
  const int idx = blockIdx.x * 256 + threadIdx.x;
  if (idx < BATCH * COUT) accum[idx] = 0.f;
  if (idx >= 9 * COUT * CIN) return;
  const int ci = idx & 31, co = (idx >> 5) & 63, tap = idx >> 11;
  const int a = tap / 3, d = tap % 3;
  wp[idx] = f2bf(wsrc[((ci * COUT + co) * 3 + (2 - a)) * 3 + (2 - d)]);
}

// Fused conv-transpose + bias + maxpool2x2 + hardtanh + partial sum.
// grid (3 w-segs, 32 h-groups, 16 b) = 1536 blocks, 256 thr = 4 waves.
// Compute: wave = (co-half = wave&1, w-tile = wave>>1); one 32x32 tile x 2 rows/t.
// Staging: rolling 6-slot ring, rows -1..6 local; T14 issue-early/write-late.
__global__ __launch_bounds__(256, 4)
void fused_conv(const float* __restrict__ x, const short* __restrict__ wp,
                const float* __restrict__ bias, float* __restrict__ accum) {
  __shared__ short lds[NSLOT * SLOT_BYTES / 2];   // 25344 B
  __shared__ float red[2][32];
  const int wb   = blockIdx.x;                    // 0..2
  const int hg   = blockIdx.y;                    // 0..31
  const int b    = blockIdx.z;                    // 0..15
  const int tid  = threadIdx.x;
  const int wave = tid >> 6;
  const int l    = tid & 63;
  const int l31  = l & 31;
  const int lh   = l >> 5;
  const int co0  = (wave & 1) * 32;
  const int wt   = wave >> 1;
  const int hbase = hg * 6;
  const int w0    = wb * WSEG;

  // B fragments: 9 taps x 2 ci-halves (36 VGPRs)
  bf16x8 bw[9][2];
  {
    const short* p = wp + (co0 + l31) * 32 + lh * 8;
    #pragma unroll
    for (int tap = 0; tap < 9; ++tap)
      #pragma unroll
      for (int hf = 0; hf < 2; ++hf)
        bw[tap][hf] = *(const bf16x8*)(p + tap * 2048 + hf * 16);
  }

  // ---- prologue: wave r stages local row r-1 (rows -1..2 -> slots 5,0,1,2)
  {
    const int lr = wave - 1;
    const int hx = hbase + lr;
    const bool hv = (unsigned)hx < H;
    const int s = (lr + 6) % 6;
    #pragma unroll
    for (int k = 0; k < 5; ++k) {
      const int q = k * 64 + l;                    // k==4: tail 256..263
      if (k < 4 || l < 8) {
        const int wi = q >> 2, g = q & 3;
        const int xc = w0 - 1 + wi;
        const bool v = hv && ((unsigned)xc < W);
        const float* src = x + (((size_t)(b * CIN + g * 8)) * H + (v ? hx : 0)) * W
                             + (v ? xc : 0);
        bf16x8 o;
        #pragma unroll
        for (int j = 0; j < 8; ++j)
          o[j] = v ? f2bf(src[(size_t)j * (H * W)]) : (short)0;
        *(bf16x8*)((char*)lds + lds_addr(s, wi, g)) = o;
      }
    }
  }
  __syncthreads();

  const float bv = bias[co0 + l31];
  float sum = 0.f;

  // staging roles per t: rw = which of 2 new rows, sub = granule half
  const int rw = wave >> 1, sub = wave & 1;

  #pragma unroll
  for (int t = 0; t < 3; ++t) {
    // ---- phase A: issue global loads for rows 2t+3, 2t+4 into regs
    float sA[8], sB[8], sC[8];
    const int lrS = 2 * t + 3 + rw;
    const int hxS = hbase + lrS;
    const bool hvS = hxS < H;
    const int qa = sub * 132 + l;          // granules [sub*132, +131]
    const int qb = qa + 64;
    const int qc = sub * 132 + 128 + l;    // only l<4
    bool vA = false, vB = false, vC = false;
    if (t < 2) {
      {
        const int wi = qa >> 2, g = qa & 3, xc = w0 - 1 + wi;
        vA = hvS && ((unsigned)xc < W);
        const float* src = x + (((size_t)(b * CIN + g * 8)) * H + (vA ? hxS : 0)) * W
                             + (vA ? xc : 0);
        #pragma unroll
        for (int j = 0; j < 8; ++j) sA[j] = vA ? src[(size_t)j * (H * W)] : 0.f;
      }
      {
        const int wi = qb >> 2, g = qb & 3, xc = w0 - 1 + wi;
        vB = hvS && ((unsigned)xc < W);
        const float* src = x + (((size_t)(b * CIN + g * 8)) * H + (vB ? hxS : 0)) * W
                             + (vB ? xc : 0);
        #pragma unroll
        for (int j = 0; j < 8; ++j) sB[j] = vB ? src[(size_t)j * (H * W)] : 0.f;
      }
      if (l < 4) {
        const int wi = qc >> 2, g = qc & 3, xc = w0 - 1 + wi;
        vC = hvS && ((unsigned)xc < W);
        const float* src = x + (((size_t)(b * CIN + g * 8)) * H + (vC ? hxS : 0)) * W
                             + (vC ? xc : 0);
        #pragma unroll
        for (int j = 0; j < 8; ++j) sC[j] = vC ? src[(size_t)j * (H * W)] : 0.f;
      }
    }

    // ---- phase B: compute conv rows 2t, 2t+1 for my (wt, co-half)
    __builtin_amdgcn_s_setprio(1);
    f32x16 acc0, acc1;
    #pragma unroll
    for (int i = 0; i < 16; ++i) { acc0[i] = 0.f; acc1[i] = 0.f; }
    #pragma unroll
    for (int xr = 0; xr < 4; ++xr) {
      const int s = (2 * t + 5 + xr) % 6;          // row 2t-1+xr
      #pragma unroll
      for (int d = 0; d < 3; ++d) {
        const int wi = wt * 32 + l31 + d;          // 0..65
        #pragma unroll
        for (int hf = 0; hf < 2; ++hf) {
          const bf16x8 af =
              *(const bf16x8*)((const char*)lds + lds_addr(s, wi, 2 * hf + lh));
          if (xr < 3)
            acc0 = __builtin_amdgcn_mfma_f32_32x32x16_bf16(af, bw[xr * 3 + d][hf], acc0, 0, 0, 0);
          if (xr > 0)
            acc1 = __builtin_amdgcn_mfma_f32_32x32x16_bf16(af, bw[(xr - 1) * 3 + d][hf], acc1, 0, 0, 0);
        }
      }
    }
    __builtin_amdgcn_s_setprio(0);

    // epilogue: regs (2g,2g+1) = w-pair, acc0/acc1 = h-pair -> 2x2 maxpool
    #pragma unroll
    for (int g = 0; g < 8; ++g) {
      float m = fmaxf(fmaxf(acc0[2 * g], acc0[2 * g + 1]),
                      fmaxf(acc1[2 * g], acc1[2 * g + 1]));
      sum += fminf(fmaxf(m + bv, -1.f), 1.f);
    }

    // ---- phase C: land staged rows (write slots disjoint from t's read slots)
    if (t < 2) {
      const int s = lrS % 6;
      {
        const int wi = qa >> 2, g = qa & 3;
        bf16x8 o;
        #pragma unroll
        for (int j = 0; j < 8; ++j) o[j] = f2bf(sA[j]);
        *(bf16x8*)((char*)lds + lds_addr(s, wi, g)) = o;
      }
      {
        const int wi = qb >> 2, g = qb & 3;
        bf16x8 o;
        #pragma unroll
        for (int j = 0; j < 8; ++j) o[j] = f2bf(sB[j]);
        *(bf16x8*)((char*)lds + lds_addr(s, wi, g)) = o;
      }
      if (l < 4) {
        const int wi = qc >> 2, g = qc & 3;
        bf16x8 o;
        #pragma unroll
        for (int j = 0; j < 8; ++j) o[j] = f2bf(sC[j]);
        *(bf16x8*)((char*)lds + lds_addr(s, wi, g)) = o;
      }
      __syncthreads();
    }
  }

  // reduce: l and l^32 share co; then cross-wave pairs (0,2) and (1,3)
  sum += __shfl_xor(sum, 32, 64);
  if (wave >= 2 && l < 32) red[wave - 2][l31] = sum;
  __syncthreads();
  if (wave < 2 && l < 32)
    atomicAdd(&accum[b * COUT + co0 + l31], sum + red[wave][l31]);
}

__global__ void finish_kernel(const float* __restrict__ accum,
                              float* __restrict__ out, int n) {
  const int i = blockIdx.x * blockDim.x + threadIdx.x;
  if (i < n) out[i] = tanhf(accum[i] * (1.0f / (96.0f * 96.0f)));
}

extern "C" void kernel_launch(void* const* d_in, const int* in_sizes, int n_in,
                              void* d_out, int out_size, void* d_ws, size_t ws_size,
                              hipStream_t stream) {
  const float* x      = (const float*)d_in[0];
  const float* weight = (const float*)d_in[1];
  const float* bias   = (const float*)d_in[2];
  float* out = (float*)d_out;

  short* wp    = (short*)d_ws;
  float* accum = (float*)((char*)d_ws + ACC_OFF);

  pack_weights<<<dim3(72), 256, 0, stream>>>(weight, wp, accum);
  fused_conv<<<dim3(3, 32, BATCH), 256, 0, stream>>>(x, wp, bias, accum);
  finish_kernel<<<dim3(1), 1024, 0, stream>>>(accum, out, BATCH * COUT);
}

// Round 7
// 216.275 us; speedup vs baseline: 1.2556x; 1.2556x over previous
//
#include <hip/hip_runtime.h>
#include <hip/hip_bf16.h>
#include <math.h>

#define H 192
#define W 192
#define CIN 32
#define COUT 64
#define BATCH 16

#define WSEG 64                     // conv cols per block
#define WI_N 66                     // staged cols (WSEG + 2 halo)
#define NSLOT 6                     // LDS row ring
#define SLOT_BYTES (WI_N * 64)      // 66 wi * 32 ci * 2B = 4224

#define WP_BYTES ((size_t)9 * COUT * CIN * 2)
#define ACC_OFF  WP_BYTES
#define ACC_BYTES ((size_t)BATCH * COUT * 4)

typedef __attribute__((ext_vector_type(8)))  short bf16x8;
typedef __attribute__((ext_vector_type(16))) float f32x16;

static __device__ __forceinline__ short f2bf(float f) {
  __hip_bfloat16 h = __float2bfloat16(f);
  return __builtin_bit_cast(short, h);
}

// slot byte addr + XOR swizzle (same forward map on write & read, bijective)
static __device__ __forceinline__ int lds_addr(int s, int wi, int g) {
  int a = s * SLOT_BYTES + wi * 64 + g * 16;
  return a ^ ((wi & 7) << 4);
}

// weight [ci][co][kh][kw] f32 -> Wp[tap][co][ci] bf16 (flipped); also zeroes accum
__global__ void pack_weights(const float* __restrict__ wsrc, short* __restrict__ wp,
                             float* __restrict__ accum) {
  const int idx = blockIdx.x * 256 + threadIdx.x;
  if (idx < BATCH * COUT) accum[idx] = 0.f;
  if (idx >= 9 * COUT * CIN) return;
  const int ci = idx & 31, co = (idx >> 5) & 63, tap = idx >> 11;
  const int a = tap / 3, d = tap % 3;
  wp[idx] = f2bf(wsrc[((ci * COUT + co) * 3 + (2 - a)) * 3 + (2 - d)]);
}

// Fused conv-transpose + bias + maxpool2x2 + hardtanh + partial sum.
// grid (3 w-segs, 32 h-groups, 16 b) = 1536 blocks, 256 thr = 4 waves.
// Compute: wave = (co-half = wave&1, w-tile = wave>>1); 32x32 tile x 2 rows/t.
// Staging: rolling 6-slot ring; T14 issue-early (phase A) / write-late (phase C).
// launch_bounds(256,3): VGPR cap 170 — round-5's (256,4) cap of ~128 caused
// 158 MB of scratch spill; demand is ~128-150, LDS permits 6 blocks/CU.
__global__ __launch_bounds__(256, 3)
void fused_conv(const float* __restrict__ x, const short* __restrict__ wp,
                const float* __restrict__ bias, float* __restrict__ accum) {
  __shared__ short lds[NSLOT * SLOT_BYTES / 2];   // 25344 B
  __shared__ float red[2][32];
  const int wb   = blockIdx.x;                    // 0..2
  const int hg   = blockIdx.y;                    // 0..31
  const int b    = blockIdx.z;                    // 0..15
  const int tid  = threadIdx.x;
  const int wave = tid >> 6;
  const int l    = tid & 63;
  const int l31  = l & 31;
  const int lh   = l >> 5;
  const int co0  = (wave & 1) * 32;
  const int wt   = wave >> 1;
  const int hbase = hg * 6;
  const int w0    = wb * WSEG;

  // B fragments: 9 taps x 2 ci-halves (36 VGPRs)
  bf16x8 bw[9][2];
  {
    const short* p = wp + (co0 + l31) * 32 + lh * 8;
    #pragma unroll
    for (int tap = 0; tap < 9; ++tap)
      #pragma unroll
      for (int hf = 0; hf < 2; ++hf)
        bw[tap][hf] = *(const bf16x8*)(p + tap * 2048 + hf * 16);
  }

  // ---- prologue: wave r stages local row r-1 (rows -1..2 -> slots 5,0,1,2)
  {
    const int lr = wave - 1;
    const int hx = hbase + lr;
    const bool hv = (unsigned)hx < H;
    const int s = (lr + 6) % 6;
    #pragma unroll
    for (int k = 0; k < 5; ++k) {
      const int q = k * 64 + l;                    // k==4: tail 256..263
      if (k < 4 || l < 8) {
        const int wi = q >> 2, g = q & 3;
        const int xc = w0 - 1 + wi;
        const bool v = hv && ((unsigned)xc < W);
        const float* src = x + (((size_t)(b * CIN + g * 8)) * H + (v ? hx : 0)) * W
                             + (v ? xc : 0);
        bf16x8 o;
        #pragma unroll
        for (int j = 0; j < 8; ++j)
          o[j] = v ? f2bf(src[(size_t)j * (H * W)]) : (short)0;
        *(bf16x8*)((char*)lds + lds_addr(s, wi, g)) = o;
      }
    }
  }
  __syncthreads();

  const float bv = bias[co0 + l31];
  float sum = 0.f;

  // staging roles per t: rw = which of 2 new rows, sub = granule half
  const int rw = wave >> 1, sub = wave & 1;

  #pragma unroll
  for (int t = 0; t < 3; ++t) {
    // ---- phase A: issue global loads for rows 2t+3, 2t+4 into regs
    float sA[8], sB[8], sC[8];
    const int lrS = 2 * t + 3 + rw;
    const int hxS = hbase + lrS;
    const bool hvS = hxS < H;
    const int qa = sub * 132 + l;          // granules [sub*132, +131]
    const int qb = qa + 64;
    const int qc = sub * 132 + 128 + l;    // only l<4
    if (t < 2) {
      {
        const int wi = qa >> 2, g = qa & 3, xc = w0 - 1 + wi;
        const bool v = hvS && ((unsigned)xc < W);
        const float* src = x + (((size_t)(b * CIN + g * 8)) * H + (v ? hxS : 0)) * W
                             + (v ? xc : 0);
        #pragma unroll
        for (int j = 0; j < 8; ++j) sA[j] = v ? src[(size_t)j * (H * W)] : 0.f;
      }
      {
        const int wi = qb >> 2, g = qb & 3, xc = w0 - 1 + wi;
        const bool v = hvS && ((unsigned)xc < W);
        const float* src = x + (((size_t)(b * CIN + g * 8)) * H + (v ? hxS : 0)) * W
                             + (v ? xc : 0);
        #pragma unroll
        for (int j = 0; j < 8; ++j) sB[j] = v ? src[(size_t)j * (H * W)] : 0.f;
      }
      if (l < 4) {
        const int wi = qc >> 2, g = qc & 3, xc = w0 - 1 + wi;
        const bool v = hvS && ((unsigned)xc < W);
        const float* src = x + (((size_t)(b * CIN + g * 8)) * H + (v ? hxS : 0)) * W
                             + (v ? xc : 0);
        #pragma unroll
        for (int j = 0; j < 8; ++j) sC[j] = v ? src[(size_t)j * (H * W)] : 0.f;
      }
    }

    // ---- phase B: compute conv rows 2t, 2t+1 for my (wt, co-half)
    __builtin_amdgcn_s_setprio(1);
    f32x16 acc0, acc1;
    #pragma unroll
    for (int i = 0; i < 16; ++i) { acc0[i] = 0.f; acc1[i] = 0.f; }
    #pragma unroll
    for (int xr = 0; xr < 4; ++xr) {
      const int s = (2 * t + 5 + xr) % 6;          // row 2t-1+xr
      #pragma unroll
      for (int d = 0; d < 3; ++d) {
        const int wi = wt * 32 + l31 + d;          // 0..65
        #pragma unroll
        for (int hf = 0; hf < 2; ++hf) {
          const bf16x8 af =
              *(const bf16x8*)((const char*)lds + lds_addr(s, wi, 2 * hf + lh));
          if (xr < 3)
            acc0 = __builtin_amdgcn_mfma_f32_32x32x16_bf16(af, bw[xr * 3 + d][hf], acc0, 0, 0, 0);
          if (xr > 0)
            acc1 = __builtin_amdgcn_mfma_f32_32x32x16_bf16(af, bw[(xr - 1) * 3 + d][hf], acc1, 0, 0, 0);
        }
      }
    }
    __builtin_amdgcn_s_setprio(0);

    // epilogue: regs (2g,2g+1) = w-pair, acc0/acc1 = h-pair -> 2x2 maxpool
    #pragma unroll
    for (int g = 0; g < 8; ++g) {
      float m = fmaxf(fmaxf(acc0[2 * g], acc0[2 * g + 1]),
                      fmaxf(acc1[2 * g], acc1[2 * g + 1]));
      sum += fminf(fmaxf(m + bv, -1.f), 1.f);
    }

    // ---- phase C: land staged rows (write slots disjoint from t's read slots)
    if (t < 2) {
      const int s = lrS % 6;
      {
        const int wi = qa >> 2, g = qa & 3;
        bf16x8 o;
        #pragma unroll
        for (int j = 0; j < 8; ++j) o[j] = f2bf(sA[j]);
        *(bf16x8*)((char*)lds + lds_addr(s, wi, g)) = o;
      }
      {
        const int wi = qb >> 2, g = qb & 3;
        bf16x8 o;
        #pragma unroll
        for (int j = 0; j < 8; ++j) o[j] = f2bf(sB[j]);
        *(bf16x8*)((char*)lds + lds_addr(s, wi, g)) = o;
      }
      if (l < 4) {
        const int wi = qc >> 2, g = qc & 3;
        bf16x8 o;
        #pragma unroll
        for (int j = 0; j < 8; ++j) o[j] = f2bf(sC[j]);
        *(bf16x8*)((char*)lds + lds_addr(s, wi, g)) = o;
      }
      __syncthreads();
    }
  }

  // reduce: l and l^32 share co; then cross-wave pairs (0,2) and (1,3)
  sum += __shfl_xor(sum, 32, 64);
  if (wave >= 2 && l < 32) red[wave - 2][l31] = sum;
  __syncthreads();
  if (wave < 2 && l < 32)
    atomicAdd(&accum[b * COUT + co0 + l31], sum + red[wave][l31]);
}

__global__ void finish_kernel(const float* __restrict__ accum,
                              float* __restrict__ out, int n) {
  const int i = blockIdx.x * blockDim.x + threadIdx.x;
  if (i < n) out[i] = tanhf(accum[i] * (1.0f / (96.0f * 96.0f)));
}

extern "C" void kernel_launch(void* const* d_in, const int* in_sizes, int n_in,
                              void* d_out, int out_size, void* d_ws, size_t ws_size,
                              hipStream_t stream) {
  const float* x      = (const float*)d_in[0];
  const float* weight = (const float*)d_in[1];
  const float* bias   = (const float*)d_in[2];
  float* out = (float*)d_out;

  short* wp    = (short*)d_ws;
  float* accum = (float*)((char*)d_ws + ACC_OFF);

  pack_weights<<<dim3(72), 256, 0, stream>>>(weight, wp, accum);
  fused_conv<<<dim3(3, 32, BATCH), 256, 0, stream>>>(x, wp, bias, accum);
  finish_kernel<<<dim3(1), 1024, 0, stream>>>(accum, out, BATCH * COUT);
}

// Round 8
// 202.207 us; speedup vs baseline: 1.3430x; 1.0696x over previous
//
#include <hip/hip_runtime.h>
#include <hip/hip_bf16.h>
#include <math.h>

#define H 192
#define W 192
#define CIN 32
#define COUT 64
#define BATCH 16

#define WSEG 64                     // conv cols per block
#define WI_N 66                     // staged cols (WSEG + 2 halo)
#define NSLOT 6                     // LDS row ring
#define SLOT_BYTES (WI_N * 64)      // 66 wi * 32 ci * 2B = 4224

#define WP_BYTES ((size_t)9 * COUT * CIN * 2)
#define ACC_OFF  WP_BYTES
#define ACC_BYTES ((size_t)BATCH * COUT * 4)

typedef __attribute__((ext_vector_type(8)))  short bf16x8;
typedef __attribute__((ext_vector_type(16))) float f32x16;

static __device__ __forceinline__ short f2bf(float f) {
  __hip_bfloat16 h = __float2bfloat16(f);
  return __builtin_bit_cast(short, h);
}

// slot byte addr + XOR swizzle (same forward map on write & read, bijective)
static __device__ __forceinline__ int lds_addr(int s, int wi, int g) {
  int a = s * SLOT_BYTES + wi * 64 + g * 16;
  return a ^ ((wi & 7) << 4);
}

// weight [ci][co][kh][kw] f32 -> Wp[tap][co][ci] bf16 (flipped); also zeroes accum
__global__ void pack_weights(const float* __restrict__ wsrc, short* __restrict__ wp,
                             float* __restrict__ accum) {
  const int idx = blockIdx.x * 256 + threadIdx.x;
  if (idx < BATCH * COUT) accum[idx] = 0.f;
  if (idx >= 9 * COUT * CIN) return;
  const int ci = idx & 31, co = (idx >> 5) & 63, tap = idx >> 11;
  const int a = tap / 3, d = tap % 3;
  wp[idx] = f2bf(wsrc[((ci * COUT + co) * 3 + (2 - a)) * 3 + (2 - d)]);
}

// Fused conv-transpose + bias + maxpool2x2 + hardtanh + partial sum.
// grid (3 w-segs, 32 h-groups, 16 b) = 1536 blocks, 256 thr = 4 waves.
// Compute: wave = (co-half = wave&1, w-tile = wave>>1); 32x32 tile x 2 rows/t.
// Staging: rolling 6-slot ring. Phase A loads next 2 rows AND converts to
// bf16x8 immediately (12 staged VGPRs, vs 24+ f32 — rounds 5/7 proved the
// f32-held variant spills ~23 dwords/thread = 90+ MB scratch). Phase C is
// pure ds_write_b128. Latency hiding comes from 12 waves/CU TLP.
__global__ __launch_bounds__(256, 3)
void fused_conv(const float* __restrict__ x, const short* __restrict__ wp,
                const float* __restrict__ bias, float* __restrict__ accum) {
  __shared__ short lds[NSLOT * SLOT_BYTES / 2];   // 25344 B
  __shared__ float red[2][32];
  const int wb   = blockIdx.x;                    // 0..2
  const int hg   = blockIdx.y;                    // 0..31
  const int b    = blockIdx.z;                    // 0..15
  const int tid  = threadIdx.x;
  const int wave = tid >> 6;
  const int l    = tid & 63;
  const int l31  = l & 31;
  const int lh   = l >> 5;
  const int co0  = (wave & 1) * 32;
  const int wt   = wave >> 1;
  const int hbase = hg * 6;
  const int w0    = wb * WSEG;

  // B fragments: 9 taps x 2 ci-halves (36 VGPRs)
  bf16x8 bw[9][2];
  {
    const short* p = wp + (co0 + l31) * 32 + lh * 8;
    #pragma unroll
    for (int tap = 0; tap < 9; ++tap)
      #pragma unroll
      for (int hf = 0; hf < 2; ++hf)
        bw[tap][hf] = *(const bf16x8*)(p + tap * 2048 + hf * 16);
  }

  // ---- prologue: wave r stages local row r-1 (rows -1..2 -> slots 5,0,1,2)
  {
    const int lr = wave - 1;
    const int hx = hbase + lr;
    const bool hv = (unsigned)hx < H;
    const int s = (lr + 6) % 6;
    #pragma unroll
    for (int k = 0; k < 5; ++k) {
      const int q = k * 64 + l;                    // k==4: tail 256..263
      if (k < 4 || l < 8) {
        const int wi = q >> 2, g = q & 3;
        const int xc = w0 - 1 + wi;
        const bool v = hv && ((unsigned)xc < W);
        const float* src = x + (((size_t)(b * CIN + g * 8)) * H + (v ? hx : 0)) * W
                             + (v ? xc : 0);
        bf16x8 o;
        #pragma unroll
        for (int j = 0; j < 8; ++j)
          o[j] = v ? f2bf(src[(size_t)j * (H * W)]) : (short)0;
        *(bf16x8*)((char*)lds + lds_addr(s, wi, g)) = o;
      }
    }
  }
  __syncthreads();

  const float bv = bias[co0 + l31];
  float sum = 0.f;

  // staging roles per t: rw = which of 2 new rows, sub = granule half
  const int rw = wave >> 1, sub = wave & 1;

  #pragma unroll
  for (int t = 0; t < 3; ++t) {
    // ---- phase A: load rows 2t+3, 2t+4 and convert to bf16 NOW (small regs)
    bf16x8 sA, sB, sC;
    const int lrS = 2 * t + 3 + rw;
    const int hxS = hbase + lrS;
    const bool hvS = hxS < H;
    const int qa = sub * 132 + l;          // granules [sub*132, +131]
    const int qb = qa + 64;
    const int qc = sub * 132 + 128 + l;    // only l<4
    if (t < 2) {
      {
        const int wi = qa >> 2, g = qa & 3, xc = w0 - 1 + wi;
        const bool v = hvS && ((unsigned)xc < W);
        const float* src = x + (((size_t)(b * CIN + g * 8)) * H + (v ? hxS : 0)) * W
                             + (v ? xc : 0);
        float tf[8];
        #pragma unroll
        for (int j = 0; j < 8; ++j) tf[j] = v ? src[(size_t)j * (H * W)] : 0.f;
        #pragma unroll
        for (int j = 0; j < 8; ++j) sA[j] = f2bf(tf[j]);
      }
      {
        const int wi = qb >> 2, g = qb & 3, xc = w0 - 1 + wi;
        const bool v = hvS && ((unsigned)xc < W);
        const float* src = x + (((size_t)(b * CIN + g * 8)) * H + (v ? hxS : 0)) * W
                             + (v ? xc : 0);
        float tf[8];
        #pragma unroll
        for (int j = 0; j < 8; ++j) tf[j] = v ? src[(size_t)j * (H * W)] : 0.f;
        #pragma unroll
        for (int j = 0; j < 8; ++j) sB[j] = f2bf(tf[j]);
      }
      if (l < 4) {
        const int wi = qc >> 2, g = qc & 3, xc = w0 - 1 + wi;
        const bool v = hvS && ((unsigned)xc < W);
        const float* src = x + (((size_t)(b * CIN + g * 8)) * H + (v ? hxS : 0)) * W
                             + (v ? xc : 0);
        float tf[8];
        #pragma unroll
        for (int j = 0; j < 8; ++j) tf[j] = v ? src[(size_t)j * (H * W)] : 0.f;
        #pragma unroll
        for (int j = 0; j < 8; ++j) sC[j] = f2bf(tf[j]);
      }
    }

    // ---- phase B: compute conv rows 2t, 2t+1 for my (wt, co-half)
    __builtin_amdgcn_s_setprio(1);
    f32x16 acc0, acc1;
    #pragma unroll
    for (int i = 0; i < 16; ++i) { acc0[i] = 0.f; acc1[i] = 0.f; }
    #pragma unroll
    for (int xr = 0; xr < 4; ++xr) {
      const int s = (2 * t + 5 + xr) % 6;          // row 2t-1+xr
      #pragma unroll
      for (int d = 0; d < 3; ++d) {
        const int wi = wt * 32 + l31 + d;          // 0..65
        #pragma unroll
        for (int hf = 0; hf < 2; ++hf) {
          const bf16x8 af =
              *(const bf16x8*)((const char*)lds + lds_addr(s, wi, 2 * hf + lh));
          if (xr < 3)
            acc0 = __builtin_amdgcn_mfma_f32_32x32x16_bf16(af, bw[xr * 3 + d][hf], acc0, 0, 0, 0);
          if (xr > 0)
            acc1 = __builtin_amdgcn_mfma_f32_32x32x16_bf16(af, bw[(xr - 1) * 3 + d][hf], acc1, 0, 0, 0);
        }
      }
    }
    __builtin_amdgcn_s_setprio(0);

    // epilogue: regs (2g,2g+1) = w-pair, acc0/acc1 = h-pair -> 2x2 maxpool
    #pragma unroll
    for (int g = 0; g < 8; ++g) {
      float m = fmaxf(fmaxf(acc0[2 * g], acc0[2 * g + 1]),
                      fmaxf(acc1[2 * g], acc1[2 * g + 1]));
      sum += fminf(fmaxf(m + bv, -1.f), 1.f);
    }

    // ---- phase C: land staged rows (write slots disjoint from t's read slots)
    if (t < 2) {
      const int s = lrS % 6;
      {
        const int wi = qa >> 2, g = qa & 3;
        *(bf16x8*)((char*)lds + lds_addr(s, wi, g)) = sA;
      }
      {
        const int wi = qb >> 2, g = qb & 3;
        *(bf16x8*)((char*)lds + lds_addr(s, wi, g)) = sB;
      }
      if (l < 4) {
        const int wi = qc >> 2, g = qc & 3;
        *(bf16x8*)((char*)lds + lds_addr(s, wi, g)) = sC;
      }
      __syncthreads();
    }
  }

  // reduce: l and l^32 share co; then cross-wave pairs (0,2) and (1,3)
  sum += __shfl_xor(sum, 32, 64);
  if (wave >= 2 && l < 32) red[wave - 2][l31] = sum;
  __syncthreads();
  if (wave < 2 && l < 32)
    atomicAdd(&accum[b * COUT + co0 + l31], sum + red[wave][l31]);
}

__global__ void finish_kernel(const float* __restrict__ accum,
                              float* __restrict__ out, int n) {
  const int i = blockIdx.x * blockDim.x + threadIdx.x;
  if (i < n) out[i] = tanhf(accum[i] * (1.0f / (96.0f * 96.0f)));
}

extern "C" void kernel_launch(void* const* d_in, const int* in_sizes, int n_in,
                              void* d_out, int out_size, void* d_ws, size_t ws_size,
                              hipStream_t stream) {
  const float* x      = (const float*)d_in[0];
  const float* weight = (const float*)d_in[1];
  const float* bias   = (const float*)d_in[2];
  float* out = (float*)d_out;

  short* wp    = (short*)d_ws;
  float* accum = (float*)((char*)d_ws + ACC_OFF);

  pack_weights<<<dim3(72), 256, 0, stream>>>(weight, wp, accum);
  fused_conv<<<dim3(3, 32, BATCH), 256, 0, stream>>>(x, wp, bias, accum);
  finish_kernel<<<dim3(1), 1024, 0, stream>>>(accum, out, BATCH * COUT);
}

// Round 10
// 169.614 us; speedup vs baseline: 1.6010x; 1.1922x over previous
//
#include <hip/hip_runtime.h>
#include <hip/hip_bf16.h>
#include <math.h>

#define H 192
#define W 192
#define CIN 32
#define COUT 64
#define BATCH 16

#define WSEG 64                     // conv cols per block
#define WI_N 66                     // staged cols (WSEG + 2 halo)
#define NSLOT 8                     // 6 conv rows + 2 halo rows, slot = xrow+1
#define SLOT_BYTES (WI_N * 64)      // 66 wi * 32 ci * 2B = 4224
#define NGRAN (NSLOT * WI_N * 4)    // 2112 granules (16B each)

#define WP_BYTES ((size_t)9 * COUT * CIN * 2)
#define ACC_OFF  WP_BYTES
#define ACC_BYTES ((size_t)BATCH * COUT * 4)

typedef __attribute__((ext_vector_type(8)))  short bf16x8;
typedef __attribute__((ext_vector_type(16))) float f32x16;

static __device__ __forceinline__ short f2bf(float f) {
  __hip_bfloat16 h = __float2bfloat16(f);
  return __builtin_bit_cast(short, h);
}

// slot byte addr + XOR swizzle (same forward map on write & read, bijective)
static __device__ __forceinline__ int lds_addr(int s, int wi, int g) {
  int a = s * SLOT_BYTES + wi * 64 + g * 16;
  return a ^ ((wi & 7) << 4);
}

// weight [ci][co][kh][kw] f32 -> Wp[tap][co][ci] bf16 (flipped); also zeroes accum
__global__ void pack_weights(const float* __restrict__ wsrc, short* __restrict__ wp,
                             float* __restrict__ accum) {
  const int idx = blockIdx.x * 256 + threadIdx.x;
  if (idx < BATCH * COUT) accum[idx] = 0.f;
  if (idx >= 9 * COUT * CIN) return;
  const int ci = idx & 31, co = (idx >> 5) & 63, tap = idx >> 11;
  const int a = tap / 3, d = tap % 3;
  wp[idx] = f2bf(wsrc[((ci * COUT + co) * 3 + (2 - a)) * 3 + (2 - d)]);
}

// Fused conv-transpose + bias + maxpool2x2 + hardtanh + partial sum.
// grid (3 w-segs, 32 h-groups, 16 b) = 1536 blocks, 256 thr = 4 waves.
// STRUCTURE (round 9): no rolling ring / no reg-pipeline (rounds 5-8 all
// spilled under the arch-VGPR budget). One flat stage of all 8 x-rows into
// 33.8 KB LDS via a #pragma unroll 1 granule loop (tiny live range), one
// barrier, then 3 h-pair compute steps with statically-indexed slots.
__global__ __launch_bounds__(256, 3)
void fused_conv(const float* __restrict__ x, const short* __restrict__ wp,
                const float* __restrict__ bias, float* __restrict__ accum) {
  __shared__ short lds[NSLOT * SLOT_BYTES / 2];   // 33792 B
  __shared__ float red[2][32];
  const int wb   = blockIdx.x;                    // 0..2
  const int hg   = blockIdx.y;                    // 0..31
  const int b    = blockIdx.z;                    // 0..15
  const int tid  = threadIdx.x;
  const int wave = tid >> 6;
  const int l    = tid & 63;
  const int l31  = l & 31;
  const int lh   = l >> 5;
  const int co0  = (wave & 1) * 32;
  const int wt   = wave >> 1;
  const int hbase = hg * 6;
  const int w0    = wb * WSEG;

  // ---- stage all 8 x-rows (hbase-1 .. hbase+6) -> LDS slots 0..7.
  // granule G = s*264 + wi*4 + g ; thread handles G = tid + 256k.
  #pragma unroll 1
  for (int k = 0; k < 9; ++k) {
    if (k < 8 || tid < NGRAN - 8 * 256) {
      const int G  = tid + k * 256;
      const int s  = G / 264;
      const int r  = G - s * 264;
      const int wi = r >> 2, g = r & 3;
      const int hx = hbase + s - 1;
      const int xc = w0 - 1 + wi;
      const bool v = ((unsigned)hx < H) && ((unsigned)xc < W);
      const float* src = x + (((size_t)(b * CIN + g * 8)) * H + (v ? hx : 0)) * W
                           + (v ? xc : 0);
      float tf[8];
      #pragma unroll
      for (int j = 0; j < 8; ++j) tf[j] = v ? src[(size_t)j * (H * W)] : 0.f;
      bf16x8 o;
      #pragma unroll
      for (int j = 0; j < 8; ++j) o[j] = f2bf(tf[j]);
      *(bf16x8*)((char*)lds + lds_addr(s, wi, g)) = o;
    }
  }

  // B fragments: 9 taps x 2 ci-halves (36 VGPRs) — overlaps with staging tail
  bf16x8 bw[9][2];
  {
    const short* p = wp + (co0 + l31) * 32 + lh * 8;
    #pragma unroll
    for (int tap = 0; tap < 9; ++tap)
      #pragma unroll
      for (int hf = 0; hf < 2; ++hf)
        bw[tap][hf] = *(const bf16x8*)(p + tap * 2048 + hf * 16);
  }

  __syncthreads();

  const float bv = bias[co0 + l31];
  float sum = 0.f;

  #pragma unroll
  for (int t = 0; t < 3; ++t) {
    // conv rows hbase+2t (acc0), hbase+2t+1 (acc1); x rows = slots 2t..2t+3
    __builtin_amdgcn_s_setprio(1);
    f32x16 acc0, acc1;
    #pragma unroll
    for (int i = 0; i < 16; ++i) { acc0[i] = 0.f; acc1[i] = 0.f; }
    #pragma unroll
    for (int xr = 0; xr < 4; ++xr) {
      const int s = 2 * t + xr;                    // static slot
      #pragma unroll
      for (int d = 0; d < 3; ++d) {
        const int wi = wt * 32 + l31 + d;          // 0..65
        #pragma unroll
        for (int hf = 0; hf < 2; ++hf) {
          const bf16x8 af =
              *(const bf16x8*)((const char*)lds + lds_addr(s, wi, 2 * hf + lh));
          if (xr < 3)
            acc0 = __builtin_amdgcn_mfma_f32_32x32x16_bf16(af, bw[xr * 3 + d][hf], acc0, 0, 0, 0);
          if (xr > 0)
            acc1 = __builtin_amdgcn_mfma_f32_32x32x16_bf16(af, bw[(xr - 1) * 3 + d][hf], acc1, 0, 0, 0);
        }
      }
    }
    __builtin_amdgcn_s_setprio(0);

    // C row = (reg&3)+8*(reg>>2)+4*lh: regs (2g,2g+1) = w-pair,
    // acc0/acc1 = h-pair -> full 2x2 maxpool in-lane.
    #pragma unroll
    for (int g = 0; g < 8; ++g) {
      float m = fmaxf(fmaxf(acc0[2 * g], acc0[2 * g + 1]),
                      fmaxf(acc1[2 * g], acc1[2 * g + 1]));
      sum += fminf(fmaxf(m + bv, -1.f), 1.f);
    }
  }

  // reduce: l and l^32 share co; then cross-wave pairs (0,2) and (1,3)
  sum += __shfl_xor(sum, 32, 64);
  if (wave >= 2 && l < 32) red[wave - 2][l31] = sum;
  __syncthreads();
  if (wave < 2 && l < 32)
    atomicAdd(&accum[b * COUT + co0 + l31], sum + red[wave][l31]);
}

__global__ void finish_kernel(const float* __restrict__ accum,
                              float* __restrict__ out, int n) {
  const int i = blockIdx.x * blockDim.x + threadIdx.x;
  if (i < n) out[i] = tanhf(accum[i] * (1.0f / (96.0f * 96.0f)));
}

extern "C" void kernel_launch(void* const* d_in, const int* in_sizes, int n_in,
                              void* d_out, int out_size, void* d_ws, size_t ws_size,
                              hipStream_t stream) {
  const float* x      = (const float*)d_in[0];
  const float* weight = (const float*)d_in[1];
  const float* bias   = (const float*)d_in[2];
  float* out = (float*)d_out;

  short* wp    = (short*)d_ws;
  float* accum = (float*)((char*)d_ws + ACC_OFF);

  pack_weights<<<dim3(72), 256, 0, stream>>>(weight, wp, accum);
  fused_conv<<<dim3(3, 32, BATCH), 256, 0, stream>>>(x, wp, bias, accum);
  finish_kernel<<<dim3(1), 1024, 0, stream>>>(accum, out, BATCH * COUT);
}